// Round 7
// baseline (494.458 us; speedup 1.0000x reference)
//
#include <hip/hip_runtime.h>
#include <math.h>

#define B_ 32
#define L_ 2049
#define E_ 1024
#define H_ 16
#define NT_ 8
#define STILE 256

// workspace layout (float offsets) — identical footprint to round 1 (known-safe)
#define OFF_Q     0
#define OFF_T     (OFF_Q + B_*E_)
#define OFF_QBK   (OFF_T + B_*H_*E_)
#define OFF_M     (OFF_QBK + B_*H_)
#define OFF_L     (OFF_M + B_*NT_*H_)
#define OFF_U     (OFF_L + B_*NT_*H_)
#define OFF_ATTN  (OFF_U + B_*H_*E_)
#define OFF_Y     (OFF_ATTN + B_*E_)
#define OFF_UP    (OFF_Y + B_*E_)

// ---------------------------------------------------------------- generic 32xE GEMM:
// C[b][j] = sum_k A[b*As + kbase + k] * W[j][k] + bias[j] (+ resid[b*Rs + j])
// mode 1 (vproj): kbase = (j>>6)*1024 (per-head slice of u). Grid: 512 blocks, j-tile=2.
__global__ __launch_bounds__(256) void k_gemm32(const float* __restrict__ A, long long As, int mode,
                                                const float* __restrict__ W,
                                                const float* __restrict__ bias,
                                                const float* __restrict__ resid, long long Rs,
                                                float* __restrict__ C) {
    __shared__ float wls[2 * 1056];  // 2 swizzled W rows
    const int j0 = blockIdx.x * 2, tid = threadIdx.x;
    #pragma unroll
    for (int k = 0; k < 2; ++k) {
        int idx4 = k * 256 + tid;
        int row = idx4 >> 8, c4 = idx4 & 255;
        float4 v = *(const float4*)(W + (size_t)(j0 + row) * E_ + 4 * c4);
        *(float4*)&wls[row * 1056 + 4 * c4 + ((c4 >> 5) << 2)] = v;  // swizzle: k + (k>>7)*4
    }
    __syncthreads();
    const int bb = tid >> 3, kseg = tid & 7;
    const long long kbase = (mode == 1) ? (long long)(j0 >> 6) * E_ : 0;
    const float* arow = A + (size_t)bb * As + kbase + kseg * 128;
    float a0 = 0.f, a1 = 0.f;
    #pragma unroll 4
    for (int i = 0; i < 32; ++i) {
        float4 av = *(const float4*)(arow + 4 * i);
        const float* wb = &wls[kseg * 132 + 4 * i];
        float4 w0 = *(const float4*)(wb);
        float4 w1 = *(const float4*)(wb + 1056);
        a0 += av.x * w0.x + av.y * w0.y + av.z * w0.z + av.w * w0.w;
        a1 += av.x * w1.x + av.y * w1.y + av.z * w1.z + av.w * w1.w;
    }
    #pragma unroll
    for (int off = 4; off; off >>= 1) {
        a0 += __shfl_down(a0, off, 8);
        a1 += __shfl_down(a1, off, 8);
    }
    if (kseg == 0) {
        float r0 = a0 + bias[j0], r1 = a1 + bias[j0 + 1];
        if (resid) {
            r0 += resid[(size_t)bb * Rs + j0];
            r1 += resid[(size_t)bb * Rs + j0 + 1];
        }
        C[(size_t)bb * E_ + j0] = r0;
        C[(size_t)bb * E_ + j0 + 1] = r1;
    }
}

// ---------------------------------------------------------------- t = 0.125*q_h@Wk_h ; qbk
// grid (16 h, 16 e-tiles of 64), 256 thr
__global__ __launch_bounds__(256) void k_tproj(const float* __restrict__ Wk,
                                               const float* __restrict__ bk,
                                               float* __restrict__ ws) {
    __shared__ float qs[64 * 33];   // [d][b]
    __shared__ float wls[64 * 68];  // [d][e] padded/aligned
    const int h = blockIdx.x, e0 = blockIdx.y * 64, tid = threadIdx.x;
    const float* q = ws + OFF_Q;
    #pragma unroll
    for (int k = 0; k < 8; ++k) {
        int idx = k * 256 + tid;
        int b = idx >> 6, d = idx & 63;
        qs[d * 33 + b] = q[(size_t)b * E_ + 64 * h + d];
    }
    #pragma unroll
    for (int k = 0; k < 4; ++k) {
        int idx4 = k * 256 + tid;
        int d = idx4 >> 4, c4 = idx4 & 15;
        float4 v = *(const float4*)(Wk + (size_t)(64 * h + d) * E_ + e0 + 4 * c4);
        *(float4*)&wls[d * 68 + 4 * c4] = v;
    }
    __syncthreads();
    const int el = tid & 63, bq8 = tid >> 6;
    float acc[8];
    #pragma unroll
    for (int i = 0; i < 8; ++i) acc[i] = 0.f;
    for (int d = 0; d < 64; ++d) {
        float wv = wls[d * 68 + el];
        #pragma unroll
        for (int i = 0; i < 8; ++i) acc[i] += qs[d * 33 + (bq8 * 8 + i)] * wv;
    }
    float* t = ws + OFF_T;
    #pragma unroll
    for (int i = 0; i < 8; ++i)
        t[((size_t)(bq8 * 8 + i) * H_ + h) * E_ + e0 + el] = acc[i] * 0.125f;
    if (e0 == 0 && tid < 32) {
        float s = 0.f;
        for (int d = 0; d < 64; ++d) s += qs[d * 33 + tid] * bk[64 * h + d];
        ws[OFF_QBK + tid * H_ + h] = s * 0.125f;
    }
}

// ---------------------------------------------------------------- fused scores/softmax/u_part
// 1024 threads (16 waves), 1 block/CU (~83 KB LDS), hard 64-VGPR budget (rounds 1-4).
// Phase 1 + softmax: round-4 proven form (x 1x from HBM, t from LDS, 16-float e-granule).
// Phase 2 (round 7): barrier-free + LANE-GROUPED weight reads. Round-6 lesson: phase 2
//   was LDS-pipe-bound on wave-UNIFORM wl broadcasts (1024 ds_read_b128/wave * 12cyc *
//   16 waves = ~82 us). New lane map: lane = (hg=lane>>4 head-quad, cl=lane&15 col-quad);
//   lane accumulates 4 heads x 4 columns. Weight read = ONE ds_read_b128 per ROW per
//   wave (4 unique addrs, banks {0,4,8,12}/{16,20,24,28}, 16-way same-addr broadcast =
//   conflict-free) -> 256 LDS instrs/wave (4x fewer). x = one global float4 per row
//   (head-groups duplicate addresses; wave coalescer dedups to 256 unique B/row).
__global__ __launch_bounds__(1024) void k_attn_core(const float* __restrict__ x,
                                                    float* __restrict__ ws) {
    const int tile = blockIdx.x, b = blockIdx.y, tid = threadIdx.x;
    const int s0t = tile * STILE;
    const float* tmat = ws + OFF_T + (size_t)b * H_ * E_;
    const float* xb = x + (size_t)(b * L_ + 1 + s0t) * E_;

    __shared__ float smem[16384];   // t[16][1024]
    __shared__ float wl[256 * 16];  // hi-half partial scores, then softmax weights [s][h]
    __shared__ float pmax[128], psum[128], msh[16];

    const int lane = tid & 63, w = tid >> 6;
    const int g = lane & 3, ssub = lane >> 2;
    const int wlo = w & 7;
    const int ehalf = (w >> 3) * 512;      // phase-1 e-half owned by this wave group
    const int sA = 32 * wlo + ssub, sB = sA + 16;

    // ---- stage full t (16x1024 = 64 KB), straight copy ----
    #pragma unroll
    for (int k = 0; k < 4; ++k) {
        int idx4 = k * 1024 + tid;
        *(float4*)&smem[4 * idx4] = *(const float4*)(tmat + 4 * idx4);
    }
    __syncthreads();

    // ================= phase 1: partial scores (no barriers inside) =================
    float acc[16][2];
    #pragma unroll
    for (int h = 0; h < 16; ++h) { acc[h][0] = 0.f; acc[h][1] = 0.f; }

    {
        // each quad lane g covers e = ehalf + 16*c + 4*g .. +3  (union over g = full half)
        const float* xA = xb + (size_t)sA * E_ + ehalf + 4 * g;
        const float* xB = xb + (size_t)sB * E_ + ehalf + 4 * g;
        const float* tb = &smem[ehalf + 4 * g];
        #pragma unroll 2
        for (int c = 0; c < 32; ++c) {
            float4 a0 = *(const float4*)(xA + 16 * c);
            float4 b0 = *(const float4*)(xB + 16 * c);
            #pragma unroll
            for (int h = 0; h < 16; ++h) {
                float4 t0 = *(const float4*)(tb + h * E_ + 16 * c);
                acc[h][0] += t0.x * a0.x + t0.y * a0.y + t0.z * a0.z + t0.w * a0.w;
                acc[h][1] += t0.x * b0.x + t0.y * b0.y + t0.z * b0.z + t0.w * b0.w;
            }
        }
    }
    // reduce over the 4 e-column lanes (g) — all 4 g-dups end with the full sum
    #pragma unroll
    for (int h = 0; h < 16; ++h) {
        #pragma unroll
        for (int s = 0; s < 2; ++s) {
            float v = acc[h][s];
            v += __shfl_xor(v, 1, 64);
            v += __shfl_xor(v, 2, 64);
            acc[h][s] = v;
        }
    }
    // hi e-half waves deposit partials into wl (g-branch picks the h-quad; static reg idx)
    if (w >= 8) {
        if (g == 0) {
            *(float4*)&wl[sA * 16 + 0]  = make_float4(acc[0][0], acc[1][0], acc[2][0], acc[3][0]);
            *(float4*)&wl[sB * 16 + 0]  = make_float4(acc[0][1], acc[1][1], acc[2][1], acc[3][1]);
        } else if (g == 1) {
            *(float4*)&wl[sA * 16 + 4]  = make_float4(acc[4][0], acc[5][0], acc[6][0], acc[7][0]);
            *(float4*)&wl[sB * 16 + 4]  = make_float4(acc[4][1], acc[5][1], acc[6][1], acc[7][1]);
        } else if (g == 2) {
            *(float4*)&wl[sA * 16 + 8]  = make_float4(acc[8][0], acc[9][0], acc[10][0], acc[11][0]);
            *(float4*)&wl[sB * 16 + 8]  = make_float4(acc[8][1], acc[9][1], acc[10][1], acc[11][1]);
        } else {
            *(float4*)&wl[sA * 16 + 12] = make_float4(acc[12][0], acc[13][0], acc[14][0], acc[15][0]);
            *(float4*)&wl[sB * 16 + 12] = make_float4(acc[12][1], acc[13][1], acc[14][1], acc[15][1]);
        }
    }
    __syncthreads();  // E1: hi partials visible; smem (t) free from here on

    // ================= softmax partials (lo waves hold full scores) =================
    if (w < 8) {
        const float* qbkp = ws + OFF_QBK + b * H_;
        #pragma unroll
        for (int h = 0; h < 16; ++h) {
            float qb = qbkp[h];
            acc[h][0] += wl[sA * 16 + h] + qb;
            acc[h][1] += wl[sB * 16 + h] + qb;
        }
        #pragma unroll
        for (int h = 0; h < 16; ++h) {
            float v = fmaxf(acc[h][0], acc[h][1]);
            v = fmaxf(v, __shfl_xor(v, 4, 64));
            v = fmaxf(v, __shfl_xor(v, 8, 64));
            v = fmaxf(v, __shfl_xor(v, 16, 64));
            v = fmaxf(v, __shfl_xor(v, 32, 64));
            if (lane == 0) pmax[w * 16 + h] = v;
        }
    }
    __syncthreads();  // B1
    if (tid < 16) {
        float M = pmax[tid];
        #pragma unroll
        for (int q = 1; q < 8; ++q) M = fmaxf(M, pmax[q * 16 + tid]);
        msh[tid] = M;
        ws[OFF_M + (size_t)(b * NT_ + tile) * H_ + tid] = M;
    }
    __syncthreads();  // B2
    if (w < 8) {
        float ex0[16], ex1[16];
        #pragma unroll
        for (int h = 0; h < 16; ++h) {
            float M = msh[h];
            ex0[h] = __expf(acc[h][0] - M);
            ex1[h] = __expf(acc[h][1] - M);
        }
        if (g == 0) {
            *(float4*)&wl[sA * 16 + 0]  = make_float4(ex0[0], ex0[1], ex0[2], ex0[3]);
            *(float4*)&wl[sB * 16 + 0]  = make_float4(ex1[0], ex1[1], ex1[2], ex1[3]);
        } else if (g == 1) {
            *(float4*)&wl[sA * 16 + 4]  = make_float4(ex0[4], ex0[5], ex0[6], ex0[7]);
            *(float4*)&wl[sB * 16 + 4]  = make_float4(ex1[4], ex1[5], ex1[6], ex1[7]);
        } else if (g == 2) {
            *(float4*)&wl[sA * 16 + 8]  = make_float4(ex0[8], ex0[9], ex0[10], ex0[11]);
            *(float4*)&wl[sB * 16 + 8]  = make_float4(ex1[8], ex1[9], ex1[10], ex1[11]);
        } else {
            *(float4*)&wl[sA * 16 + 12] = make_float4(ex0[12], ex0[13], ex0[14], ex0[15]);
            *(float4*)&wl[sB * 16 + 12] = make_float4(ex1[12], ex1[13], ex1[14], ex1[15]);
        }
        #pragma unroll
        for (int h = 0; h < 16; ++h) {
            float v = ex0[h] + ex1[h];
            v += __shfl_xor(v, 4, 64);
            v += __shfl_xor(v, 8, 64);
            v += __shfl_xor(v, 16, 64);
            v += __shfl_xor(v, 32, 64);
            if (lane == 0) psum[w * 16 + h] = v;
        }
    }
    __syncthreads();  // B3: weights complete in wl
    if (tid < 16) {
        float Ls = 0.f;
        #pragma unroll
        for (int q = 0; q < 8; ++q) Ls += psum[q * 16 + tid];
        ws[OFF_L + (size_t)(b * NT_ + tile) * H_ + tid] = Ls;
    }

    // ================= phase 2 (barrier-free, lane-grouped): u[h][e] ================
    // lane = (hg, cl): 4 heads (4*hg..+3) x 4 columns (64w + 4*cl..+3) per lane.
    const int hg = lane >> 4, cl = lane & 15;
    float4 ua0 = make_float4(0.f, 0.f, 0.f, 0.f);
    float4 ua1 = make_float4(0.f, 0.f, 0.f, 0.f);
    float4 ua2 = make_float4(0.f, 0.f, 0.f, 0.f);
    float4 ua3 = make_float4(0.f, 0.f, 0.f, 0.f);
    const float* xq2 = xb + 64 * w + 4 * cl;
    const float* wq2 = &wl[4 * hg];

#define P2ROW(WV, XV)                                                                   \
    ua0.x += WV.x * XV.x; ua0.y += WV.x * XV.y; ua0.z += WV.x * XV.z; ua0.w += WV.x * XV.w; \
    ua1.x += WV.y * XV.x; ua1.y += WV.y * XV.y; ua1.z += WV.y * XV.z; ua1.w += WV.y * XV.w; \
    ua2.x += WV.z * XV.x; ua2.y += WV.z * XV.y; ua2.z += WV.z * XV.z; ua2.w += WV.z * XV.w; \
    ua3.x += WV.w * XV.x; ua3.y += WV.w * XV.y; ua3.z += WV.w * XV.z; ua3.w += WV.w * XV.w;

    #pragma unroll 1
    for (int r4 = 0; r4 < 64; ++r4) {
        const int r = 4 * r4;
        float4 xv0 = *(const float4*)(xq2 + (size_t)(r + 0) * E_);
        float4 xv1 = *(const float4*)(xq2 + (size_t)(r + 1) * E_);
        float4 xv2 = *(const float4*)(xq2 + (size_t)(r + 2) * E_);
        float4 xv3 = *(const float4*)(xq2 + (size_t)(r + 3) * E_);
        float4 w0 = *(const float4*)(wq2 + (r + 0) * 16);
        float4 w1 = *(const float4*)(wq2 + (r + 1) * 16);
        float4 w2 = *(const float4*)(wq2 + (r + 2) * 16);
        float4 w3 = *(const float4*)(wq2 + (r + 3) * 16);
        P2ROW(w0, xv0)
        P2ROW(w1, xv1)
        P2ROW(w2, xv2)
        P2ROW(w3, xv3)
    }
#undef P2ROW

    float* up = ws + OFF_UP + ((size_t)((b * NT_ + tile) * H_ + 4 * hg)) * E_ + 64 * w + 4 * cl;
    *(float4*)(up)          = ua0;
    *(float4*)(up + E_)     = ua1;
    *(float4*)(up + 2 * E_) = ua2;
    *(float4*)(up + 3 * E_) = ua3;
}

// ---------------------------------------------------------------- combine partial tiles
__global__ __launch_bounds__(256) void k_combine(float* __restrict__ ws) {
    const int b = blockIdx.x, h = blockIdx.y, tid = threadIdx.x;
    float m[NT_], l[NT_], f[NT_];
    float M = -1e30f;
    #pragma unroll
    for (int tg = 0; tg < NT_; ++tg) {
        m[tg] = ws[OFF_M + (b * NT_ + tg) * H_ + h];
        l[tg] = ws[OFF_L + (b * NT_ + tg) * H_ + h];
        M = fmaxf(M, m[tg]);
    }
    float Ls = 0.f;
    #pragma unroll
    for (int tg = 0; tg < NT_; ++tg) {
        f[tg] = __expf(m[tg] - M);
        Ls += f[tg] * l[tg];
    }
    const float inv = 1.f / Ls;
    float4 a = make_float4(0.f, 0.f, 0.f, 0.f);
    #pragma unroll
    for (int tg = 0; tg < NT_; ++tg) {
        float4 v = *(const float4*)(ws + OFF_UP + (size_t)((b * NT_ + tg) * H_ + h) * E_ + 4 * tid);
        a.x += f[tg] * v.x; a.y += f[tg] * v.y; a.z += f[tg] * v.z; a.w += f[tg] * v.w;
    }
    a.x *= inv; a.y *= inv; a.z *= inv; a.w *= inv;
    *(float4*)(ws + OFF_U + (size_t)(b * H_ + h) * E_ + 4 * tid) = a;
}

// ---------------------------------------------------------------- LayerNorm -> out
__global__ __launch_bounds__(256) void k_ln(const float* __restrict__ ws,
                                            const float* __restrict__ g,
                                            const float* __restrict__ be,
                                            float* __restrict__ out) {
    const int b = blockIdx.x, tid = threadIdx.x;
    const float* y = ws + OFF_Y + (size_t)b * E_;
    float4 v = *(const float4*)(y + 4 * tid);
    float s = v.x + v.y + v.z + v.w;
    float s2 = v.x * v.x + v.y * v.y + v.z * v.z + v.w * v.w;
    for (int o = 32; o; o >>= 1) {
        s += __shfl_down(s, o, 64);
        s2 += __shfl_down(s2, o, 64);
    }
    __shared__ float rs[4], rs2[4];
    int ww = tid >> 6;
    if ((tid & 63) == 0) { rs[ww] = s; rs2[ww] = s2; }
    __syncthreads();
    float S = rs[0] + rs[1] + rs[2] + rs[3];
    float S2 = rs2[0] + rs2[1] + rs2[2] + rs2[3];
    float mean = S * (1.f / 1024.f);
    float var = S2 * (1.f / 1024.f) - mean * mean;
    float r = rsqrtf(var + 1e-5f);
    float4 gv = *(const float4*)(g + 4 * tid);
    float4 bb2 = *(const float4*)(be + 4 * tid);
    float4 o;
    o.x = (v.x - mean) * r * gv.x + bb2.x;
    o.y = (v.y - mean) * r * gv.y + bb2.y;
    o.z = (v.z - mean) * r * gv.z + bb2.z;
    o.w = (v.w - mean) * r * gv.w + bb2.w;
    *(float4*)(out + (size_t)b * E_ + 4 * tid) = o;
}

extern "C" void kernel_launch(void* const* d_in, const int* in_sizes, int n_in,
                              void* d_out, int out_size, void* d_ws, size_t ws_size,
                              hipStream_t stream) {
    const float* x  = (const float*)d_in[0];
    const float* Wq = (const float*)d_in[1];
    const float* bq = (const float*)d_in[2];
    const float* Wk = (const float*)d_in[3];
    const float* bk = (const float*)d_in[4];
    const float* Wv = (const float*)d_in[5];
    const float* bv = (const float*)d_in[6];
    const float* Wo = (const float*)d_in[7];
    const float* bo = (const float*)d_in[8];
    const float* g  = (const float*)d_in[9];
    const float* be = (const float*)d_in[10];
    float* ws = (float*)d_ws;
    float* out = (float*)d_out;

    // q = cls @ Wq^T + bq
    k_gemm32<<<512, 256, 0, stream>>>(x, (long long)L_ * E_, 0, Wq, bq, nullptr, 0, ws + OFF_Q);
    // t = 0.125 * q_h @ Wk_h ; qbk
    k_tproj<<<dim3(16, 16), 256, 0, stream>>>(Wk, bk, ws);
    // fused attention core (1024 threads, 16 waves/CU)
    k_attn_core<<<dim3(NT_, B_), 1024, 0, stream>>>(x, ws);
    // combine softmax tiles
    k_combine<<<dim3(B_, H_), 256, 0, stream>>>(ws);
    // attn = Wv_h @ u_h + bv   (per-head K slice of u)
    k_gemm32<<<512, 256, 0, stream>>>(ws + OFF_U, (long long)H_ * E_, 1, Wv, bv, nullptr, 0, ws + OFF_ATTN);
    // y = attn @ Wo^T + bo + cls
    k_gemm32<<<512, 256, 0, stream>>>(ws + OFF_ATTN, (long long)E_, 0, Wo, bo, x, (long long)L_ * E_, ws + OFF_Y);
    // LayerNorm
    k_ln<<<B_, 256, 0, stream>>>(ws, g, be, out);
}

// Round 8
// 490.457 us; speedup vs baseline: 1.0082x; 1.0082x over previous
//
#include <hip/hip_runtime.h>
#include <math.h>

#define B_ 32
#define L_ 2049
#define E_ 1024
#define H_ 16
#define NT_ 8
#define STILE 256

// workspace layout (float offsets) — identical footprint to round 1 (known-safe)
#define OFF_Q     0
#define OFF_T     (OFF_Q + B_*E_)
#define OFF_QBK   (OFF_T + B_*H_*E_)
#define OFF_M     (OFF_QBK + B_*H_)
#define OFF_L     (OFF_M + B_*NT_*H_)
#define OFF_U     (OFF_L + B_*NT_*H_)
#define OFF_ATTN  (OFF_U + B_*H_*E_)
#define OFF_Y     (OFF_ATTN + B_*E_)
#define OFF_UP    (OFF_Y + B_*E_)

// ---------------------------------------------------------------- generic 32xE GEMM:
// C[b][j] = sum_k A[b*As + kbase + k] * W[j][k] + bias[j] (+ resid[b*Rs + j])
// mode 1 (vproj): kbase = (j>>6)*1024 (per-head slice of u). Grid: 512 blocks, j-tile=2.
__global__ __launch_bounds__(256) void k_gemm32(const float* __restrict__ A, long long As, int mode,
                                                const float* __restrict__ W,
                                                const float* __restrict__ bias,
                                                const float* __restrict__ resid, long long Rs,
                                                float* __restrict__ C) {
    __shared__ float wls[2 * 1056];  // 2 swizzled W rows
    const int j0 = blockIdx.x * 2, tid = threadIdx.x;
    #pragma unroll
    for (int k = 0; k < 2; ++k) {
        int idx4 = k * 256 + tid;
        int row = idx4 >> 8, c4 = idx4 & 255;
        float4 v = *(const float4*)(W + (size_t)(j0 + row) * E_ + 4 * c4);
        *(float4*)&wls[row * 1056 + 4 * c4 + ((c4 >> 5) << 2)] = v;  // swizzle: k + (k>>7)*4
    }
    __syncthreads();
    const int bb = tid >> 3, kseg = tid & 7;
    const long long kbase = (mode == 1) ? (long long)(j0 >> 6) * E_ : 0;
    const float* arow = A + (size_t)bb * As + kbase + kseg * 128;
    float a0 = 0.f, a1 = 0.f;
    #pragma unroll 4
    for (int i = 0; i < 32; ++i) {
        float4 av = *(const float4*)(arow + 4 * i);
        const float* wb = &wls[kseg * 132 + 4 * i];
        float4 w0 = *(const float4*)(wb);
        float4 w1 = *(const float4*)(wb + 1056);
        a0 += av.x * w0.x + av.y * w0.y + av.z * w0.z + av.w * w0.w;
        a1 += av.x * w1.x + av.y * w1.y + av.z * w1.z + av.w * w1.w;
    }
    #pragma unroll
    for (int off = 4; off; off >>= 1) {
        a0 += __shfl_down(a0, off, 8);
        a1 += __shfl_down(a1, off, 8);
    }
    if (kseg == 0) {
        float r0 = a0 + bias[j0], r1 = a1 + bias[j0 + 1];
        if (resid) {
            r0 += resid[(size_t)bb * Rs + j0];
            r1 += resid[(size_t)bb * Rs + j0 + 1];
        }
        C[(size_t)bb * E_ + j0] = r0;
        C[(size_t)bb * E_ + j0 + 1] = r1;
    }
}

// ---------------------------------------------------------------- t = 0.125*q_h@Wk_h ; qbk
// grid (16 h, 16 e-tiles of 64), 256 thr
__global__ __launch_bounds__(256) void k_tproj(const float* __restrict__ Wk,
                                               const float* __restrict__ bk,
                                               float* __restrict__ ws) {
    __shared__ float qs[64 * 33];   // [d][b]
    __shared__ float wls[64 * 68];  // [d][e] padded/aligned
    const int h = blockIdx.x, e0 = blockIdx.y * 64, tid = threadIdx.x;
    const float* q = ws + OFF_Q;
    #pragma unroll
    for (int k = 0; k < 8; ++k) {
        int idx = k * 256 + tid;
        int b = idx >> 6, d = idx & 63;
        qs[d * 33 + b] = q[(size_t)b * E_ + 64 * h + d];
    }
    #pragma unroll
    for (int k = 0; k < 4; ++k) {
        int idx4 = k * 256 + tid;
        int d = idx4 >> 4, c4 = idx4 & 15;
        float4 v = *(const float4*)(Wk + (size_t)(64 * h + d) * E_ + e0 + 4 * c4);
        *(float4*)&wls[d * 68 + 4 * c4] = v;
    }
    __syncthreads();
    const int el = tid & 63, bq8 = tid >> 6;
    float acc[8];
    #pragma unroll
    for (int i = 0; i < 8; ++i) acc[i] = 0.f;
    for (int d = 0; d < 64; ++d) {
        float wv = wls[d * 68 + el];
        #pragma unroll
        for (int i = 0; i < 8; ++i) acc[i] += qs[d * 33 + (bq8 * 8 + i)] * wv;
    }
    float* t = ws + OFF_T;
    #pragma unroll
    for (int i = 0; i < 8; ++i)
        t[((size_t)(bq8 * 8 + i) * H_ + h) * E_ + e0 + el] = acc[i] * 0.125f;
    if (e0 == 0 && tid < 32) {
        float s = 0.f;
        for (int d = 0; d < 64; ++d) s += qs[d * 33 + tid] * bk[64 * h + d];
        ws[OFF_QBK + tid * H_ + h] = s * 0.125f;
    }
}

// ---------------------------------------------------------------- fused scores/softmax/u_part
// Round-8: back to 512 threads (8 waves). Rounds 4-7 showed the 1024-thread 64-VGPR
// budget is the real limiter: three different LDS-traffic reductions (r5/r6/r7) were
// all neutral at 165-175 us — the kernel is dependence-latency-bound because every
// loop had to run at minimal ILP to fit 64 VGPRs. 512-thread blocks get ~120 VGPRs
// (round-0 precedent: VGPR_Count=120, no spills), buying back ILP:
//   Phase 1: wave = (e-half, s-quarter); lane: g=lane&3 e-granule, rows ssub+16k
//     (k=0..3, interleaved to keep the round-4 conflict-free deposit). acc[16][4]
//     (64 VGPR) -> t-reads per FMA halved vs round 4, x still 1x from HBM.
//   Phase 2: barrier-free; wave owns 128 cols; lane = (hg=lane>>4 head-quad,
//     cl=lane&15 col-octet). 4 heads x 8 cols/lane, 4-deep row unroll.
__global__ __launch_bounds__(512) void k_attn_core(const float* __restrict__ x,
                                                   float* __restrict__ ws) {
    const int tile = blockIdx.x, b = blockIdx.y, tid = threadIdx.x;
    const int s0t = tile * STILE;
    const float* tmat = ws + OFF_T + (size_t)b * H_ * E_;
    const float* xb = x + (size_t)(b * L_ + 1 + s0t) * E_;

    __shared__ float smem[16384];   // t[16][1024]
    __shared__ float wl[256 * 16];  // hi-half partial scores, then softmax weights [s][h]
    __shared__ float pmax[64], psum[64], msh[16];

    const int lane = tid & 63, w = tid >> 6;
    const int g = lane & 3, ssub = lane >> 2;

    // ---- stage full t (16x1024 = 64 KB), straight copy ----
    #pragma unroll
    for (int k = 0; k < 8; ++k) {
        int idx4 = k * 512 + tid;
        *(float4*)&smem[4 * idx4] = *(const float4*)(tmat + 4 * idx4);
    }
    __syncthreads();

    // ================= phase 1: partial scores (no barriers inside) =================
    // wave = (eh1 e-half, sq1 s-quarter); lane row k: sq1*64 + ssub + 16k
    const int eh1 = w >> 2, sq1 = w & 3;
    const int ehalf = eh1 * 512;
    const int rbase1 = sq1 * 64 + ssub;

    float acc[16][4];
    #pragma unroll
    for (int h = 0; h < 16; ++h) {
        acc[h][0] = 0.f; acc[h][1] = 0.f; acc[h][2] = 0.f; acc[h][3] = 0.f;
    }
    {
        const float* xq = xb + (size_t)rbase1 * E_ + ehalf + 4 * g;
        const float* tb = &smem[ehalf + 4 * g];
        #pragma unroll 1
        for (int c = 0; c < 32; ++c) {
            const int e0 = 16 * c;
            float4 x0 = *(const float4*)(xq + e0);
            float4 x1 = *(const float4*)(xq + 16 * E_ + e0);
            float4 x2 = *(const float4*)(xq + 32 * E_ + e0);
            float4 x3 = *(const float4*)(xq + 48 * E_ + e0);
            #pragma unroll
            for (int h = 0; h < 16; ++h) {
                float4 t0 = *(const float4*)(tb + h * E_ + e0);
                acc[h][0] += t0.x * x0.x + t0.y * x0.y + t0.z * x0.z + t0.w * x0.w;
                acc[h][1] += t0.x * x1.x + t0.y * x1.y + t0.z * x1.z + t0.w * x1.w;
                acc[h][2] += t0.x * x2.x + t0.y * x2.y + t0.z * x2.z + t0.w * x2.w;
                acc[h][3] += t0.x * x3.x + t0.y * x3.y + t0.z * x3.z + t0.w * x3.w;
            }
        }
    }
    // reduce over the 4 e-granule lanes (g); all g-lanes end with the full sums
    #pragma unroll
    for (int h = 0; h < 16; ++h) {
        #pragma unroll
        for (int k = 0; k < 4; ++k) {
            float v = acc[h][k];
            v += __shfl_xor(v, 1, 64);
            v += __shfl_xor(v, 2, 64);
            acc[h][k] = v;
        }
    }
    // hi e-half waves deposit partials into wl (g picks the h-quad; static reg idx)
    if (eh1 == 1) {
        #pragma unroll
        for (int k = 0; k < 4; ++k) {
            const int row = rbase1 + 16 * k;
            if (g == 0)      *(float4*)&wl[row * 16 + 0]  = make_float4(acc[0][k],  acc[1][k],  acc[2][k],  acc[3][k]);
            else if (g == 1) *(float4*)&wl[row * 16 + 4]  = make_float4(acc[4][k],  acc[5][k],  acc[6][k],  acc[7][k]);
            else if (g == 2) *(float4*)&wl[row * 16 + 8]  = make_float4(acc[8][k],  acc[9][k],  acc[10][k], acc[11][k]);
            else             *(float4*)&wl[row * 16 + 12] = make_float4(acc[12][k], acc[13][k], acc[14][k], acc[15][k]);
        }
    }
    __syncthreads();  // E1: hi partials visible

    // ================= softmax partials (lo e-half waves hold full scores) ==========
    if (eh1 == 0) {
        const float* qbkp = ws + OFF_QBK + b * H_;
        #pragma unroll
        for (int h = 0; h < 16; ++h) {
            float qb = qbkp[h];
            #pragma unroll
            for (int k = 0; k < 4; ++k)
                acc[h][k] += wl[(rbase1 + 16 * k) * 16 + h] + qb;
        }
        #pragma unroll
        for (int h = 0; h < 16; ++h) {
            float v = fmaxf(fmaxf(acc[h][0], acc[h][1]), fmaxf(acc[h][2], acc[h][3]));
            v = fmaxf(v, __shfl_xor(v, 4, 64));
            v = fmaxf(v, __shfl_xor(v, 8, 64));
            v = fmaxf(v, __shfl_xor(v, 16, 64));
            v = fmaxf(v, __shfl_xor(v, 32, 64));
            if (lane == 0) pmax[sq1 * 16 + h] = v;
        }
    }
    __syncthreads();  // B1
    if (tid < 16) {
        float M = pmax[tid];
        M = fmaxf(M, pmax[16 + tid]);
        M = fmaxf(M, pmax[32 + tid]);
        M = fmaxf(M, pmax[48 + tid]);
        msh[tid] = M;
        ws[OFF_M + (size_t)(b * NT_ + tile) * H_ + tid] = M;
    }
    __syncthreads();  // B2
    if (eh1 == 0) {
        #pragma unroll
        for (int h = 0; h < 16; ++h) {
            float M = msh[h];
            acc[h][0] = __expf(acc[h][0] - M);
            acc[h][1] = __expf(acc[h][1] - M);
            acc[h][2] = __expf(acc[h][2] - M);
            acc[h][3] = __expf(acc[h][3] - M);
        }
        #pragma unroll
        for (int k = 0; k < 4; ++k) {
            const int row = rbase1 + 16 * k;
            if (g == 0)      *(float4*)&wl[row * 16 + 0]  = make_float4(acc[0][k],  acc[1][k],  acc[2][k],  acc[3][k]);
            else if (g == 1) *(float4*)&wl[row * 16 + 4]  = make_float4(acc[4][k],  acc[5][k],  acc[6][k],  acc[7][k]);
            else if (g == 2) *(float4*)&wl[row * 16 + 8]  = make_float4(acc[8][k],  acc[9][k],  acc[10][k], acc[11][k]);
            else             *(float4*)&wl[row * 16 + 12] = make_float4(acc[12][k], acc[13][k], acc[14][k], acc[15][k]);
        }
        #pragma unroll
        for (int h = 0; h < 16; ++h) {
            float v = acc[h][0] + acc[h][1] + acc[h][2] + acc[h][3];
            v += __shfl_xor(v, 4, 64);
            v += __shfl_xor(v, 8, 64);
            v += __shfl_xor(v, 16, 64);
            v += __shfl_xor(v, 32, 64);
            if (lane == 0) psum[sq1 * 16 + h] = v;
        }
    }
    __syncthreads();  // B3: weights complete in wl
    if (tid < 16) {
        float Ls = psum[tid] + psum[16 + tid] + psum[32 + tid] + psum[48 + tid];
        ws[OFF_L + (size_t)(b * NT_ + tile) * H_ + tid] = Ls;
    }

    // ================= phase 2 (barrier-free): u[h][e] = sum_s w[s][h]*x[s][e] ======
    // wave w owns cols [128w,128w+128); lane = (hg head-quad, cl col-octet).
    const int hg = lane >> 4, cl = lane & 15;
    float4 ua[4][2];
    #pragma unroll
    for (int j = 0; j < 4; ++j) {
        ua[j][0] = make_float4(0.f, 0.f, 0.f, 0.f);
        ua[j][1] = make_float4(0.f, 0.f, 0.f, 0.f);
    }
    const float* xq2 = xb + 128 * w + 8 * cl;
    const float* wq2 = &wl[4 * hg];
    #pragma unroll 4
    for (int r = 0; r < 256; ++r) {
        float4 xv0 = *(const float4*)(xq2 + (size_t)r * E_);
        float4 xv1 = *(const float4*)(xq2 + (size_t)r * E_ + 4);
        float4 wv = *(const float4*)(wq2 + r * 16);
        ua[0][0].x += wv.x * xv0.x; ua[0][0].y += wv.x * xv0.y; ua[0][0].z += wv.x * xv0.z; ua[0][0].w += wv.x * xv0.w;
        ua[0][1].x += wv.x * xv1.x; ua[0][1].y += wv.x * xv1.y; ua[0][1].z += wv.x * xv1.z; ua[0][1].w += wv.x * xv1.w;
        ua[1][0].x += wv.y * xv0.x; ua[1][0].y += wv.y * xv0.y; ua[1][0].z += wv.y * xv0.z; ua[1][0].w += wv.y * xv0.w;
        ua[1][1].x += wv.y * xv1.x; ua[1][1].y += wv.y * xv1.y; ua[1][1].z += wv.y * xv1.z; ua[1][1].w += wv.y * xv1.w;
        ua[2][0].x += wv.z * xv0.x; ua[2][0].y += wv.z * xv0.y; ua[2][0].z += wv.z * xv0.z; ua[2][0].w += wv.z * xv0.w;
        ua[2][1].x += wv.z * xv1.x; ua[2][1].y += wv.z * xv1.y; ua[2][1].z += wv.z * xv1.z; ua[2][1].w += wv.z * xv1.w;
        ua[3][0].x += wv.w * xv0.x; ua[3][0].y += wv.w * xv0.y; ua[3][0].z += wv.w * xv0.z; ua[3][0].w += wv.w * xv0.w;
        ua[3][1].x += wv.w * xv1.x; ua[3][1].y += wv.w * xv1.y; ua[3][1].z += wv.w * xv1.z; ua[3][1].w += wv.w * xv1.w;
    }
    float* up = ws + OFF_UP + ((size_t)((b * NT_ + tile) * H_ + 4 * hg)) * E_ + 128 * w + 8 * cl;
    #pragma unroll
    for (int j = 0; j < 4; ++j) {
        *(float4*)(up + (size_t)j * E_)     = ua[j][0];
        *(float4*)(up + (size_t)j * E_ + 4) = ua[j][1];
    }
}

// ---------------------------------------------------------------- combine partial tiles
__global__ __launch_bounds__(256) void k_combine(float* __restrict__ ws) {
    const int b = blockIdx.x, h = blockIdx.y, tid = threadIdx.x;
    float m[NT_], l[NT_], f[NT_];
    float M = -1e30f;
    #pragma unroll
    for (int tg = 0; tg < NT_; ++tg) {
        m[tg] = ws[OFF_M + (b * NT_ + tg) * H_ + h];
        l[tg] = ws[OFF_L + (b * NT_ + tg) * H_ + h];
        M = fmaxf(M, m[tg]);
    }
    float Ls = 0.f;
    #pragma unroll
    for (int tg = 0; tg < NT_; ++tg) {
        f[tg] = __expf(m[tg] - M);
        Ls += f[tg] * l[tg];
    }
    const float inv = 1.f / Ls;
    float4 a = make_float4(0.f, 0.f, 0.f, 0.f);
    #pragma unroll
    for (int tg = 0; tg < NT_; ++tg) {
        float4 v = *(const float4*)(ws + OFF_UP + (size_t)((b * NT_ + tg) * H_ + h) * E_ + 4 * tid);
        a.x += f[tg] * v.x; a.y += f[tg] * v.y; a.z += f[tg] * v.z; a.w += f[tg] * v.w;
    }
    a.x *= inv; a.y *= inv; a.z *= inv; a.w *= inv;
    *(float4*)(ws + OFF_U + (size_t)(b * H_ + h) * E_ + 4 * tid) = a;
}

// ---------------------------------------------------------------- LayerNorm -> out
__global__ __launch_bounds__(256) void k_ln(const float* __restrict__ ws,
                                            const float* __restrict__ g,
                                            const float* __restrict__ be,
                                            float* __restrict__ out) {
    const int b = blockIdx.x, tid = threadIdx.x;
    const float* y = ws + OFF_Y + (size_t)b * E_;
    float4 v = *(const float4*)(y + 4 * tid);
    float s = v.x + v.y + v.z + v.w;
    float s2 = v.x * v.x + v.y * v.y + v.z * v.z + v.w * v.w;
    for (int o = 32; o; o >>= 1) {
        s += __shfl_down(s, o, 64);
        s2 += __shfl_down(s2, o, 64);
    }
    __shared__ float rs[4], rs2[4];
    int ww = tid >> 6;
    if ((tid & 63) == 0) { rs[ww] = s; rs2[ww] = s2; }
    __syncthreads();
    float S = rs[0] + rs[1] + rs[2] + rs[3];
    float S2 = rs2[0] + rs2[1] + rs2[2] + rs2[3];
    float mean = S * (1.f / 1024.f);
    float var = S2 * (1.f / 1024.f) - mean * mean;
    float r = rsqrtf(var + 1e-5f);
    float4 gv = *(const float4*)(g + 4 * tid);
    float4 bb2 = *(const float4*)(be + 4 * tid);
    float4 o;
    o.x = (v.x - mean) * r * gv.x + bb2.x;
    o.y = (v.y - mean) * r * gv.y + bb2.y;
    o.z = (v.z - mean) * r * gv.z + bb2.z;
    o.w = (v.w - mean) * r * gv.w + bb2.w;
    *(float4*)(out + (size_t)b * E_ + 4 * tid) = o;
}

extern "C" void kernel_launch(void* const* d_in, const int* in_sizes, int n_in,
                              void* d_out, int out_size, void* d_ws, size_t ws_size,
                              hipStream_t stream) {
    const float* x  = (const float*)d_in[0];
    const float* Wq = (const float*)d_in[1];
    const float* bq = (const float*)d_in[2];
    const float* Wk = (const float*)d_in[3];
    const float* bk = (const float*)d_in[4];
    const float* Wv = (const float*)d_in[5];
    const float* bv = (const float*)d_in[6];
    const float* Wo = (const float*)d_in[7];
    const float* bo = (const float*)d_in[8];
    const float* g  = (const float*)d_in[9];
    const float* be = (const float*)d_in[10];
    float* ws = (float*)d_ws;
    float* out = (float*)d_out;

    // q = cls @ Wq^T + bq
    k_gemm32<<<512, 256, 0, stream>>>(x, (long long)L_ * E_, 0, Wq, bq, nullptr, 0, ws + OFF_Q);
    // t = 0.125 * q_h @ Wk_h ; qbk
    k_tproj<<<dim3(16, 16), 256, 0, stream>>>(Wk, bk, ws);
    // fused attention core (512 threads, 8 waves, ~120 VGPR budget)
    k_attn_core<<<dim3(NT_, B_), 512, 0, stream>>>(x, ws);
    // combine softmax tiles
    k_combine<<<dim3(B_, H_), 256, 0, stream>>>(ws);
    // attn = Wv_h @ u_h + bv   (per-head K slice of u)
    k_gemm32<<<512, 256, 0, stream>>>(ws + OFF_U, (long long)H_ * E_, 1, Wv, bv, nullptr, 0, ws + OFF_ATTN);
    // y = attn @ Wo^T + bo + cls
    k_gemm32<<<512, 256, 0, stream>>>(ws + OFF_ATTN, (long long)E_, 0, Wo, bo, x, (long long)L_ * E_, ws + OFF_Y);
    // LayerNorm
    k_ln<<<B_, 256, 0, stream>>>(ws, g, be, out);
}